// Round 1
// baseline (293.127 us; speedup 1.0000x reference)
//
#include <hip/hip_runtime.h>
#include <math.h>

#define N_NODES 1024
#define F_IN 256
#define HD 256
#define DZ 64
#define MH 128

// ---- degree accumulation (segment_sum of edge weights by col, + self loops) ----
__global__ void deg_kernel(const int* __restrict__ ei, const float* __restrict__ ew,
                           float* __restrict__ deg, int E) {
    int idx = blockIdx.x * blockDim.x + threadIdx.x;
    int ET = E + N_NODES;
    if (idx >= ET) return;
    if (idx < E) {
        int c = ei[E + idx];           // edge_index[1][e]
        atomicAdd(&deg[c], ew[idx]);
    } else {
        atomicAdd(&deg[idx - E], 1.0f); // self loop weight 1
    }
}

__global__ void dinv_kernel(float* deg) {
    int i = blockIdx.x * blockDim.x + threadIdx.x;
    if (i < N_NODES) {
        float d = deg[i];
        deg[i] = d > 0.0f ? rsqrtf(d) : 0.0f;
    }
}

// ---- simple tiled fp32 GEMM: C[M,Nc] = A[M,K] @ B[K,Nc(ldb)] (+bias) (+relu) ----
__global__ void gemm16(const float* __restrict__ A, const float* __restrict__ B,
                       const float* __restrict__ bias, float* __restrict__ C,
                       int M, int K, int Nc, int ldb, int relu) {
    __shared__ float As[16][17];
    __shared__ float Bs[16][17];
    int tx = threadIdx.x, ty = threadIdx.y;
    int row = blockIdx.y * 16 + ty;
    int col = blockIdx.x * 16 + tx;
    float acc = 0.f;
    for (int k0 = 0; k0 < K; k0 += 16) {
        As[ty][tx] = A[row * K + k0 + tx];
        Bs[ty][tx] = B[(k0 + ty) * ldb + col];
        __syncthreads();
#pragma unroll
        for (int kk = 0; kk < 16; ++kk) acc += As[ty][kk] * Bs[kk][tx];
        __syncthreads();
    }
    if (bias) acc += bias[col];
    if (relu) acc = fmaxf(acc, 0.f);
    C[row * Nc + col] = acc;
}

// ---- edge scatter: agg[col] += dinv[row]*w*dinv[col] * h[row], float4 per thread ----
template <int F, int LOGC>
__global__ void scatter_kernel(const int* __restrict__ ei, const float* __restrict__ ew,
                               const float* __restrict__ dinv, const float* __restrict__ h,
                               float* __restrict__ agg, int E) {
    int idx = blockIdx.x * blockDim.x + threadIdx.x;
    int ET = E + N_NODES;
    int total = ET << LOGC;
    if (idx >= total) return;
    int eid = idx >> LOGC;
    int f4 = (idx & ((1 << LOGC) - 1)) << 2;
    int r, c; float w;
    if (eid < E) { r = ei[eid]; c = ei[E + eid]; w = ew[eid]; }
    else         { r = eid - E; c = r; w = 1.0f; }
    float norm = dinv[r] * w * dinv[c];
    const float4 v = *reinterpret_cast<const float4*>(&h[r * F + f4]);
    float* dst = &agg[c * F + f4];
    atomicAdd(dst + 0, norm * v.x);
    atomicAdd(dst + 1, norm * v.y);
    atomicAdd(dst + 2, norm * v.z);
    atomicAdd(dst + 3, norm * v.w);
}

// ---- elementwise bias (+optional relu), in place ----
__global__ void bias_act_kernel(float* __restrict__ buf, const float* __restrict__ bias,
                                int total, int mask, int relu) {
    int idx = blockIdx.x * blockDim.x + threadIdx.x;
    if (idx >= total) return;
    float v = buf[idx] + bias[idx & mask];
    buf[idx] = relu ? fmaxf(v, 0.f) : v;
}

// ---- decoder: adj[i][j] = sigmoid( sum_h relu(A'[i][h]+B[j][h]) * w[h] + db2 ) ----
// A' already has db1 folded in (A-GEMM epilogue bias).
__global__ void decoder_kernel(const float* __restrict__ Adec, const float* __restrict__ Bdec,
                               const float* __restrict__ dW2, const float* __restrict__ db2,
                               float* __restrict__ adj) {
    __shared__ float As[16][132];   // pad 128->132: breaks stride-128 bank conflict
    __shared__ float Bs[16][132];
    __shared__ float wv[128];
    int tx = threadIdx.x, ty = threadIdx.y;
    int tid = ty * 16 + tx;
    int i0 = blockIdx.y * 16, j0 = blockIdx.x * 16;
    for (int t = tid; t < 16 * 128; t += 256) {
        int r = t >> 7, h = t & 127;
        As[r][h] = Adec[(i0 + r) * MH + h];
        Bs[r][h] = Bdec[(j0 + r) * MH + h];
    }
    if (tid < 128) wv[tid] = dW2[tid];
    __syncthreads();
    float s = 0.f;
#pragma unroll
    for (int h = 0; h < 128; h += 4) {
        float4 a = *reinterpret_cast<float4*>(&As[ty][h]);
        float4 b = *reinterpret_cast<float4*>(&Bs[tx][h]);
        float4 w = *reinterpret_cast<float4*>(&wv[h]);
        s += fmaxf(a.x + b.x, 0.f) * w.x;
        s += fmaxf(a.y + b.y, 0.f) * w.y;
        s += fmaxf(a.z + b.z, 0.f) * w.z;
        s += fmaxf(a.w + b.w, 0.f) * w.w;
    }
    s += db2[0];
    float sig = 1.0f / (1.0f + __expf(-s));
    adj[(i0 + ty) * N_NODES + j0 + tx] = sig;
}

extern "C" void kernel_launch(void* const* d_in, const int* in_sizes, int n_in,
                              void* d_out, int out_size, void* d_ws, size_t ws_size,
                              hipStream_t stream) {
    const float* x   = (const float*)d_in[0];
    const int*   ei  = (const int*)  d_in[1];
    const float* ew  = (const float*)d_in[2];
    const float* W1  = (const float*)d_in[3];
    const float* b1  = (const float*)d_in[4];
    const float* W2  = (const float*)d_in[5];
    const float* b2  = (const float*)d_in[6];
    const float* dW1 = (const float*)d_in[7];
    const float* db1 = (const float*)d_in[8];
    const float* dW2 = (const float*)d_in[9];
    const float* db2 = (const float*)d_in[10];
    int E = in_sizes[2];
    int ET = E + N_NODES;

    // workspace layout (floats)
    float* ws    = (float*)d_ws;
    float* deg   = ws;                       // 1024  (becomes dinv in place)
    float* hlin1 = ws + 1024;                // 1024*256
    float* agg1  = hlin1 + N_NODES * HD;     // 1024*256 (becomes h1 in place)
    float* hlin2 = agg1 + N_NODES * HD;      // 1024*64
    float* Adec  = hlin2 + N_NODES * DZ;     // 1024*128
    float* Bdec  = Adec + N_NODES * MH;      // 1024*128

    float* z   = (float*)d_out;              // 1024*64
    float* adj = z + N_NODES * DZ;           // 1024*1024

    hipMemsetAsync(deg, 0, N_NODES * sizeof(float), stream);
    hipMemsetAsync(agg1, 0, N_NODES * HD * sizeof(float), stream);
    hipMemsetAsync(z, 0, N_NODES * DZ * sizeof(float), stream);

    deg_kernel<<<(ET + 255) / 256, 256, 0, stream>>>(ei, ew, deg, E);
    dinv_kernel<<<(N_NODES + 255) / 256, 256, 0, stream>>>(deg);

    // layer 1: hlin1 = x @ W1 ; agg ; h1 = relu(agg + b1)
    gemm16<<<dim3(HD / 16, N_NODES / 16), dim3(16, 16), 0, stream>>>(
        x, W1, nullptr, hlin1, N_NODES, F_IN, HD, HD, 0);
    {
        int total = ET * (F_IN / 4);
        scatter_kernel<F_IN, 6><<<(total + 255) / 256, 256, 0, stream>>>(
            ei, ew, deg, hlin1, agg1, E);
    }
    bias_act_kernel<<<(N_NODES * HD + 255) / 256, 256, 0, stream>>>(
        agg1, b1, N_NODES * HD, HD - 1, 1);

    // layer 2: hlin2 = h1 @ W2 ; agg into z ; z += b2
    gemm16<<<dim3(DZ / 16, N_NODES / 16), dim3(16, 16), 0, stream>>>(
        agg1, W2, nullptr, hlin2, N_NODES, HD, DZ, DZ, 0);
    {
        int total = ET * (DZ / 4);
        scatter_kernel<DZ, 4><<<(total + 255) / 256, 256, 0, stream>>>(
            ei, ew, deg, hlin2, z, E);
    }
    bias_act_kernel<<<(N_NODES * DZ + 255) / 256, 256, 0, stream>>>(
        z, b2, N_NODES * DZ, DZ - 1, 0);

    // decoder: Adec = z @ dW1[:64] + db1 ; Bdec = z @ dW1[64:]
    gemm16<<<dim3(MH / 16, N_NODES / 16), dim3(16, 16), 0, stream>>>(
        z, dW1, db1, Adec, N_NODES, DZ, MH, MH, 0);
    gemm16<<<dim3(MH / 16, N_NODES / 16), dim3(16, 16), 0, stream>>>(
        z, dW1 + DZ * MH, nullptr, Bdec, N_NODES, DZ, MH, MH, 0);

    decoder_kernel<<<dim3(N_NODES / 16, N_NODES / 16), dim3(16, 16), 0, stream>>>(
        Adec, Bdec, dW2, db2, adj);
}

// Round 2
// 197.517 us; speedup vs baseline: 1.4841x; 1.4841x over previous
//
#include <hip/hip_runtime.h>
#include <math.h>

#define N_NODES 1024
#define F_IN 256
#define HD 256
#define DZ 64
#define MH 128

// ---------- degree: deg[c] = sum of w over edges into c (self-loop +1 added in dinv) ----------
__global__ void deg_kernel(const int* __restrict__ ei, const float* __restrict__ ew,
                           float* __restrict__ deg, int E) {
    int e = blockIdx.x * blockDim.x + threadIdx.x;
    if (e >= E) return;
    atomicAdd(&deg[ei[E + e]], ew[e]);
}

__global__ void dinv_kernel(float* deg) {
    int i = blockIdx.x * blockDim.x + threadIdx.x;
    if (i < N_NODES) deg[i] = rsqrtf(deg[i] + 1.0f);   // +1 = self loop, always > 0
}

// ---------- CSR build: histogram by col, exclusive scan, bucket fill ----------
__global__ void hist_kernel(const int* __restrict__ ei, int* __restrict__ count, int E) {
    int e = blockIdx.x * blockDim.x + threadIdx.x;
    if (e >= E) return;
    atomicAdd(&count[ei[E + e]], 1);
}

__global__ void scan_kernel(const int* __restrict__ count, int* __restrict__ start) {
    __shared__ int tmp[N_NODES];
    int t = threadIdx.x;
    tmp[t] = count[t];
    __syncthreads();
    for (int off = 1; off < N_NODES; off <<= 1) {
        int v = (t >= off) ? tmp[t - off] : 0;
        __syncthreads();
        tmp[t] += v;
        __syncthreads();
    }
    start[t + 1] = tmp[t];          // inclusive -> start[i+1]
    if (t == 0) start[0] = 0;
}

__global__ void fill_kernel(const int* __restrict__ ei, const float* __restrict__ ew,
                            const float* __restrict__ dinv, const int* __restrict__ start,
                            int* __restrict__ cursor, int* __restrict__ srcrow,
                            float* __restrict__ enorm, int E) {
    int e = blockIdx.x * blockDim.x + threadIdx.x;
    if (e >= E) return;
    int r = ei[e], c = ei[E + e];
    int idx = start[c] + atomicAdd(&cursor[c], 1);
    srcrow[idx] = r;
    enorm[idx] = dinv[r] * ew[e] * dinv[c];
}

// ---------- gather: out[c][f] = sum_in norm*h[row][f] (+self loop) (+bias)(+relu) ----------
// One 64-lane-multiple group per node; lane = feature. No atomics, coalesced reads.
template <int F, int NPB>
__global__ __launch_bounds__(256) void gather_kernel(
        const int* __restrict__ start, const int* __restrict__ srcrow,
        const float* __restrict__ enorm, const float* __restrict__ dinv,
        const float* __restrict__ h, const float* __restrict__ bias,
        float* __restrict__ out, int relu) {
    int node = blockIdx.x * NPB + threadIdx.x / F;
    int f = threadIdx.x % F;
    int s = start[node], e = start[node + 1];
    float di = dinv[node];
    float acc = di * di * h[node * F + f];          // self loop (w=1)
    for (int k = s; k < e; ++k)
        acc += enorm[k] * h[srcrow[k] * F + f];
    float v = acc + bias[f];
    out[node * F + f] = relu ? fmaxf(v, 0.f) : v;
}

// ---------- GEMM: 64x64 tile, 256 threads, 4x4 per thread, K-step 16 ----------
__global__ __launch_bounds__(256) void gemm64(const float* __restrict__ A,
        const float* __restrict__ B, const float* __restrict__ bias,
        float* __restrict__ C, int M, int K, int Nc, int relu) {
    __shared__ float As[16][68];
    __shared__ float Bs[16][68];
    int tx = threadIdx.x, ty = threadIdx.y;
    int tid = ty * 16 + tx;
    int m0 = blockIdx.y * 64, n0 = blockIdx.x * 64;
    float acc[4][4] = {};
    for (int k0 = 0; k0 < K; k0 += 16) {
#pragma unroll
        for (int i = 0; i < 4; ++i) {
            int idx = tid + i * 256;
            int r = idx >> 4, kk = idx & 15;
            As[kk][r] = A[(m0 + r) * K + k0 + kk];
            int kb = idx >> 6, c = idx & 63;
            Bs[kb][c] = B[(k0 + kb) * Nc + n0 + c];
        }
        __syncthreads();
#pragma unroll
        for (int kk = 0; kk < 16; ++kk) {
            float4 a = *(float4*)&As[kk][ty * 4];
            float4 b = *(float4*)&Bs[kk][tx * 4];
            float av[4] = {a.x, a.y, a.z, a.w};
            float bv[4] = {b.x, b.y, b.z, b.w};
#pragma unroll
            for (int i = 0; i < 4; ++i)
#pragma unroll
                for (int j = 0; j < 4; ++j) acc[i][j] += av[i] * bv[j];
        }
        __syncthreads();
    }
#pragma unroll
    for (int i = 0; i < 4; ++i) {
        int row = m0 + ty * 4 + i;
#pragma unroll
        for (int j = 0; j < 4; ++j) {
            int col = n0 + tx * 4 + j;
            float v = acc[i][j];
            if (bias) v += bias[col];
            if (relu) v = fmaxf(v, 0.f);
            C[row * Nc + col] = v;
        }
    }
}

// ---------- decoder: 32x32 tile, 2x2 per thread ----------
// adj[i][j] = sigmoid( sum_h relu(A'[i][h]+B[j][h]) * w[h] + db2 ), db1 folded into A'.
__global__ __launch_bounds__(256) void decoder_kernel(
        const float* __restrict__ Adec, const float* __restrict__ Bdec,
        const float* __restrict__ dW2, const float* __restrict__ db2,
        float* __restrict__ adj) {
    __shared__ float As[32][132];
    __shared__ float Bs[32][132];
    __shared__ float wv[128];
    int tx = threadIdx.x, ty = threadIdx.y;
    int tid = ty * 16 + tx;
    int i0 = blockIdx.y * 32, j0 = blockIdx.x * 32;
    for (int t = tid; t < 32 * 32; t += 256) {        // t -> (row, float4-of-h)
        int r = t >> 5, hh = (t & 31) << 2;
        *(float4*)&As[r][hh] = *(const float4*)&Adec[(i0 + r) * MH + hh];
        *(float4*)&Bs[r][hh] = *(const float4*)&Bdec[(j0 + r) * MH + hh];
    }
    if (tid < 32) *(float4*)&wv[tid * 4] = *(const float4*)&dW2[tid * 4];
    __syncthreads();
    float s00 = 0.f, s01 = 0.f, s10 = 0.f, s11 = 0.f;
#pragma unroll
    for (int h = 0; h < 128; h += 4) {
        float4 a0 = *(float4*)&As[ty * 2][h];
        float4 a1 = *(float4*)&As[ty * 2 + 1][h];
        float4 b0 = *(float4*)&Bs[tx * 2][h];
        float4 b1 = *(float4*)&Bs[tx * 2 + 1][h];
        float4 w = *(float4*)&wv[h];
        s00 += fmaxf(a0.x + b0.x, 0.f) * w.x + fmaxf(a0.y + b0.y, 0.f) * w.y
             + fmaxf(a0.z + b0.z, 0.f) * w.z + fmaxf(a0.w + b0.w, 0.f) * w.w;
        s01 += fmaxf(a0.x + b1.x, 0.f) * w.x + fmaxf(a0.y + b1.y, 0.f) * w.y
             + fmaxf(a0.z + b1.z, 0.f) * w.z + fmaxf(a0.w + b1.w, 0.f) * w.w;
        s10 += fmaxf(a1.x + b0.x, 0.f) * w.x + fmaxf(a1.y + b0.y, 0.f) * w.y
             + fmaxf(a1.z + b0.z, 0.f) * w.z + fmaxf(a1.w + b0.w, 0.f) * w.w;
        s11 += fmaxf(a1.x + b1.x, 0.f) * w.x + fmaxf(a1.y + b1.y, 0.f) * w.y
             + fmaxf(a1.z + b1.z, 0.f) * w.z + fmaxf(a1.w + b1.w, 0.f) * w.w;
    }
    float b2v = db2[0];
    int ri = i0 + ty * 2, cj = j0 + tx * 2;
    adj[ri * N_NODES + cj]           = 1.f / (1.f + __expf(-(s00 + b2v)));
    adj[ri * N_NODES + cj + 1]       = 1.f / (1.f + __expf(-(s01 + b2v)));
    adj[(ri + 1) * N_NODES + cj]     = 1.f / (1.f + __expf(-(s10 + b2v)));
    adj[(ri + 1) * N_NODES + cj + 1] = 1.f / (1.f + __expf(-(s11 + b2v)));
}

extern "C" void kernel_launch(void* const* d_in, const int* in_sizes, int n_in,
                              void* d_out, int out_size, void* d_ws, size_t ws_size,
                              hipStream_t stream) {
    const float* x   = (const float*)d_in[0];
    const int*   ei  = (const int*)  d_in[1];
    const float* ew  = (const float*)d_in[2];
    const float* W1  = (const float*)d_in[3];
    const float* b1  = (const float*)d_in[4];
    const float* W2  = (const float*)d_in[5];
    const float* b2  = (const float*)d_in[6];
    const float* dW1 = (const float*)d_in[7];
    const float* db1 = (const float*)d_in[8];
    const float* dW2 = (const float*)d_in[9];
    const float* db2 = (const float*)d_in[10];
    int E = in_sizes[2];

    // workspace layout
    float* ws    = (float*)d_ws;
    float* deg   = ws;                         // 1024 f (becomes dinv)
    int*   count = (int*)(ws + 1024);          // 1024 i
    int*   cursor= count + N_NODES;            // 1024 i
    int*   start = cursor + N_NODES;           // 1025 i (+pad)
    int*   srcrow= start + N_NODES + 32;       // E i
    float* enorm = (float*)(srcrow + E);       // E f
    float* hlin1 = enorm + E;                  // 1024*256
    float* h1    = hlin1 + N_NODES * HD;       // 1024*256
    float* hlin2 = h1 + N_NODES * HD;          // 1024*64
    float* Adec  = hlin2 + N_NODES * DZ;       // 1024*128
    float* Bdec  = Adec + N_NODES * MH;        // 1024*128

    float* z   = (float*)d_out;                // 1024*64
    float* adj = z + N_NODES * DZ;             // 1024*1024

    // zero deg + count + cursor in one shot (contiguous)
    hipMemsetAsync(deg, 0, (1024 + 2 * N_NODES) * sizeof(float), stream);

    deg_kernel<<<(E + 255) / 256, 256, 0, stream>>>(ei, ew, deg, E);
    dinv_kernel<<<N_NODES / 256, 256, 0, stream>>>(deg);
    hist_kernel<<<(E + 255) / 256, 256, 0, stream>>>(ei, count, E);
    scan_kernel<<<1, N_NODES, 0, stream>>>(count, start);
    fill_kernel<<<(E + 255) / 256, 256, 0, stream>>>(ei, ew, deg, start, cursor,
                                                     srcrow, enorm, E);

    // layer 1: hlin1 = x @ W1 ; h1 = relu(gather(hlin1) + b1)
    gemm64<<<dim3(HD / 64, N_NODES / 64), dim3(16, 16), 0, stream>>>(
        x, W1, nullptr, hlin1, N_NODES, F_IN, HD, 0);
    gather_kernel<HD, 1><<<N_NODES, 256, 0, stream>>>(
        start, srcrow, enorm, deg, hlin1, b1, h1, 1);

    // layer 2: hlin2 = h1 @ W2 ; z = gather(hlin2) + b2
    gemm64<<<dim3(DZ / 64, N_NODES / 64), dim3(16, 16), 0, stream>>>(
        h1, W2, nullptr, hlin2, N_NODES, HD, DZ, 0);
    gather_kernel<DZ, 4><<<N_NODES / 4, 256, 0, stream>>>(
        start, srcrow, enorm, deg, hlin2, b2, z, 0);

    // decoder GEMMs: Adec = z @ dW1[:64] + db1 ; Bdec = z @ dW1[64:]
    gemm64<<<dim3(MH / 64, N_NODES / 64), dim3(16, 16), 0, stream>>>(
        z, dW1, db1, Adec, N_NODES, DZ, MH, 0);
    gemm64<<<dim3(MH / 64, N_NODES / 64), dim3(16, 16), 0, stream>>>(
        z, dW1 + DZ * MH, nullptr, Bdec, N_NODES, DZ, MH, 0);

    decoder_kernel<<<dim3(N_NODES / 32, N_NODES / 32), dim3(16, 16), 0, stream>>>(
        Adec, Bdec, dW2, db2, adj);
}

// Round 3
// 155.384 us; speedup vs baseline: 1.8865x; 1.2712x over previous
//
#include <hip/hip_runtime.h>
#include <math.h>

#define N_NODES 1024
#define F_IN 256
#define HD 256
#define DZ 64
#define MH 128

// ---------- fused degree + histogram (atomics over 1024 destinations) ----------
__global__ void deg_hist_kernel(const int* __restrict__ ei, const float* __restrict__ ew,
                                float* __restrict__ deg, int* __restrict__ count, int E) {
    int e = blockIdx.x * blockDim.x + threadIdx.x;
    if (e >= E) return;
    int c = ei[E + e];
    atomicAdd(&deg[c], ew[e]);
    atomicAdd(&count[c], 1);
}

// ---------- fused dinv + exclusive scan (one 1024-thread block) ----------
__global__ void dinv_scan_kernel(float* __restrict__ deg, const int* __restrict__ count,
                                 int* __restrict__ start) {
    __shared__ int tmp[N_NODES];
    int t = threadIdx.x;
    deg[t] = rsqrtf(deg[t] + 1.0f);        // +1 = self loop, always > 0
    tmp[t] = count[t];
    __syncthreads();
    for (int off = 1; off < N_NODES; off <<= 1) {
        int v = (t >= off) ? tmp[t - off] : 0;
        __syncthreads();
        tmp[t] += v;
        __syncthreads();
    }
    start[t + 1] = tmp[t];
    if (t == 0) start[0] = 0;
}

__global__ void fill_kernel(const int* __restrict__ ei, const float* __restrict__ ew,
                            const float* __restrict__ dinv, const int* __restrict__ start,
                            int* __restrict__ cursor, int* __restrict__ srcrow,
                            float* __restrict__ enorm, int E) {
    int e = blockIdx.x * blockDim.x + threadIdx.x;
    if (e >= E) return;
    int r = ei[e], c = ei[E + e];
    int idx = start[c] + atomicAdd(&cursor[c], 1);
    srcrow[idx] = r;
    enorm[idx] = dinv[r] * ew[e] * dinv[c];
}

// ---------- GEMM: 64x64 tile, 256 threads, 4x4 per thread, K-step 16 ----------
__global__ __launch_bounds__(256) void gemm64(const float* __restrict__ A,
        const float* __restrict__ B, float* __restrict__ C, int K, int Nc) {
    __shared__ float As[16][68];
    __shared__ float Bs[16][68];
    int tx = threadIdx.x, ty = threadIdx.y;
    int tid = ty * 16 + tx;
    int m0 = blockIdx.y * 64, n0 = blockIdx.x * 64;
    float acc[4][4] = {};
    for (int k0 = 0; k0 < K; k0 += 16) {
#pragma unroll
        for (int i = 0; i < 4; ++i) {
            int idx = tid + i * 256;
            int r = idx >> 4, kk = idx & 15;
            As[kk][r] = A[(m0 + r) * K + k0 + kk];
            int kb = idx >> 6, c = idx & 63;
            Bs[kb][c] = B[(k0 + kb) * Nc + n0 + c];
        }
        __syncthreads();
#pragma unroll
        for (int kk = 0; kk < 16; ++kk) {
            float4 a = *(float4*)&As[kk][ty * 4];
            float4 b = *(float4*)&Bs[kk][tx * 4];
            float av[4] = {a.x, a.y, a.z, a.w};
            float bv[4] = {b.x, b.y, b.z, b.w};
#pragma unroll
            for (int i = 0; i < 4; ++i)
#pragma unroll
                for (int j = 0; j < 4; ++j) acc[i][j] += av[i] * bv[j];
        }
        __syncthreads();
    }
#pragma unroll
    for (int i = 0; i < 4; ++i) {
        int row = m0 + ty * 4 + i;
#pragma unroll
        for (int j = 0; j < 4; ++j)
            C[row * Nc + n0 + tx * 4 + j] = acc[i][j];
    }
}

// ---------- fused: h1[node] = relu(gather(hlin1)+b1) ; hlin2[node] = h1[node] @ W2 ----------
// One block per node. Phase A: 256 lanes = 256 features gather. Phase B: 4-way K-split matvec.
__global__ __launch_bounds__(256) void gather_gemm2_kernel(
        const int* __restrict__ start, const int* __restrict__ srcrow,
        const float* __restrict__ enorm, const float* __restrict__ dinv,
        const float* __restrict__ hlin1, const float* __restrict__ b1,
        const float* __restrict__ W2, float* __restrict__ hlin2) {
    __shared__ float h1s[HD];
    __shared__ float part[4][DZ];
    int node = blockIdx.x;
    int f = threadIdx.x;
    int s = start[node], e = start[node + 1];
    float di = dinv[node];
    float acc = di * di * hlin1[node * HD + f];      // self loop
    for (int k = s; k < e; ++k)
        acc += enorm[k] * hlin1[srcrow[k] * HD + f];
    h1s[f] = fmaxf(acc + b1[f], 0.f);
    __syncthreads();
    int c = f & 63, q = f >> 6;                      // wave q handles k in [64q, 64q+64)
    float p = 0.f;
#pragma unroll
    for (int k = 0; k < 64; ++k)
        p += h1s[q * 64 + k] * W2[(q * 64 + k) * DZ + c];   // h1s broadcast, W2 coalesced
    part[q][c] = p;
    __syncthreads();
    if (f < 64)
        hlin2[node * DZ + f] = part[0][f] + part[1][f] + part[2][f] + part[3][f];
}

// ---------- fused: z[node] = gather(hlin2)+b2 ; Adec = z@dW1[:64]+db1 ; Bdec = z@dW1[64:] ----------
// One block per 4 nodes: wave w gathers node w (lane = feature). Then 256 threads = 2 halves x 128 cols.
__global__ __launch_bounds__(256) void gather_dec_kernel(
        const int* __restrict__ start, const int* __restrict__ srcrow,
        const float* __restrict__ enorm, const float* __restrict__ dinv,
        const float* __restrict__ hlin2, const float* __restrict__ b2,
        const float* __restrict__ dW1, const float* __restrict__ db1,
        float* __restrict__ z, float* __restrict__ Adec, float* __restrict__ Bdec) {
    __shared__ float zs[4][DZ];
    int tid = threadIdx.x;
    int nl = tid >> 6, f = tid & 63;
    int node = blockIdx.x * 4 + nl;
    int s = start[node], e = start[node + 1];
    float di = dinv[node];
    float acc = di * di * hlin2[node * DZ + f];
    for (int k = s; k < e; ++k)
        acc += enorm[k] * hlin2[srcrow[k] * DZ + f];
    acc += b2[f];
    z[node * DZ + f] = acc;
    zs[nl][f] = acc;
    __syncthreads();
    int half = tid >> 7;                              // 0 -> Adec, 1 -> Bdec
    int c = tid & 127;
    float o0 = 0.f, o1 = 0.f, o2 = 0.f, o3 = 0.f;
#pragma unroll
    for (int k = 0; k < 64; ++k) {
        float w = dW1[(half * 64 + k) * MH + c];      // each dW1 elem read once per block
        o0 += zs[0][k] * w;
        o1 += zs[1][k] * w;
        o2 += zs[2][k] * w;
        o3 += zs[3][k] * w;
    }
    float bb = half ? 0.f : db1[c];
    float* outbuf = half ? Bdec : Adec;
    int n0 = blockIdx.x * 4;
    outbuf[(n0 + 0) * MH + c] = o0 + bb;
    outbuf[(n0 + 1) * MH + c] = o1 + bb;
    outbuf[(n0 + 2) * MH + c] = o2 + bb;
    outbuf[(n0 + 3) * MH + c] = o3 + bb;
}

// ---------- decoder: 32x32 tile, 2x2 per thread ----------
__global__ __launch_bounds__(256) void decoder_kernel(
        const float* __restrict__ Adec, const float* __restrict__ Bdec,
        const float* __restrict__ dW2, const float* __restrict__ db2,
        float* __restrict__ adj) {
    __shared__ float As[32][132];
    __shared__ float Bs[32][132];
    __shared__ float wv[128];
    int tx = threadIdx.x, ty = threadIdx.y;
    int tid = ty * 16 + tx;
    int i0 = blockIdx.y * 32, j0 = blockIdx.x * 32;
    for (int t = tid; t < 32 * 32; t += 256) {
        int r = t >> 5, hh = (t & 31) << 2;
        *(float4*)&As[r][hh] = *(const float4*)&Adec[(i0 + r) * MH + hh];
        *(float4*)&Bs[r][hh] = *(const float4*)&Bdec[(j0 + r) * MH + hh];
    }
    if (tid < 32) *(float4*)&wv[tid * 4] = *(const float4*)&dW2[tid * 4];
    __syncthreads();
    float s00 = 0.f, s01 = 0.f, s10 = 0.f, s11 = 0.f;
#pragma unroll
    for (int h = 0; h < 128; h += 4) {
        float4 a0 = *(float4*)&As[ty * 2][h];
        float4 a1 = *(float4*)&As[ty * 2 + 1][h];
        float4 b0 = *(float4*)&Bs[tx * 2][h];
        float4 b1 = *(float4*)&Bs[tx * 2 + 1][h];
        float4 w = *(float4*)&wv[h];
        s00 += fmaxf(a0.x + b0.x, 0.f) * w.x + fmaxf(a0.y + b0.y, 0.f) * w.y
             + fmaxf(a0.z + b0.z, 0.f) * w.z + fmaxf(a0.w + b0.w, 0.f) * w.w;
        s01 += fmaxf(a0.x + b1.x, 0.f) * w.x + fmaxf(a0.y + b1.y, 0.f) * w.y
             + fmaxf(a0.z + b1.z, 0.f) * w.z + fmaxf(a0.w + b1.w, 0.f) * w.w;
        s10 += fmaxf(a1.x + b0.x, 0.f) * w.x + fmaxf(a1.y + b0.y, 0.f) * w.y
             + fmaxf(a1.z + b0.z, 0.f) * w.z + fmaxf(a1.w + b0.w, 0.f) * w.w;
        s11 += fmaxf(a1.x + b1.x, 0.f) * w.x + fmaxf(a1.y + b1.y, 0.f) * w.y
             + fmaxf(a1.z + b1.z, 0.f) * w.z + fmaxf(a1.w + b1.w, 0.f) * w.w;
    }
    float b2v = db2[0];
    int ri = i0 + ty * 2, cj = j0 + tx * 2;
    adj[ri * N_NODES + cj]           = 1.f / (1.f + __expf(-(s00 + b2v)));
    adj[ri * N_NODES + cj + 1]       = 1.f / (1.f + __expf(-(s01 + b2v)));
    adj[(ri + 1) * N_NODES + cj]     = 1.f / (1.f + __expf(-(s10 + b2v)));
    adj[(ri + 1) * N_NODES + cj + 1] = 1.f / (1.f + __expf(-(s11 + b2v)));
}

extern "C" void kernel_launch(void* const* d_in, const int* in_sizes, int n_in,
                              void* d_out, int out_size, void* d_ws, size_t ws_size,
                              hipStream_t stream) {
    const float* x   = (const float*)d_in[0];
    const int*   ei  = (const int*)  d_in[1];
    const float* ew  = (const float*)d_in[2];
    const float* W1  = (const float*)d_in[3];
    const float* b1  = (const float*)d_in[4];
    const float* W2  = (const float*)d_in[5];
    const float* b2  = (const float*)d_in[6];
    const float* dW1 = (const float*)d_in[7];
    const float* db1 = (const float*)d_in[8];
    const float* dW2 = (const float*)d_in[9];
    const float* db2 = (const float*)d_in[10];
    int E = in_sizes[2];

    // workspace layout
    float* ws    = (float*)d_ws;
    float* deg   = ws;                         // 1024 f (becomes dinv)
    int*   count = (int*)(ws + N_NODES);       // 1024 i
    int*   cursor= count + N_NODES;            // 1024 i
    int*   start = cursor + N_NODES;           // 1025 i (+pad)
    int*   srcrow= start + N_NODES + 32;       // E i
    float* enorm = (float*)(srcrow + E);       // E f
    float* hlin1 = enorm + E;                  // 1024*256
    float* hlin2 = hlin1 + N_NODES * HD;       // 1024*64
    float* Adec  = hlin2 + N_NODES * DZ;       // 1024*128
    float* Bdec  = Adec + N_NODES * MH;        // 1024*128

    float* z   = (float*)d_out;                // 1024*64
    float* adj = z + N_NODES * DZ;             // 1024*1024

    // zero deg + count + cursor (contiguous, 12 KB)
    hipMemsetAsync(deg, 0, 3 * N_NODES * sizeof(float), stream);

    deg_hist_kernel<<<(E + 255) / 256, 256, 0, stream>>>(ei, ew, deg, count, E);
    dinv_scan_kernel<<<1, N_NODES, 0, stream>>>(deg, count, start);
    fill_kernel<<<(E + 255) / 256, 256, 0, stream>>>(ei, ew, deg, start, cursor,
                                                     srcrow, enorm, E);

    // hlin1 = x @ W1
    gemm64<<<dim3(HD / 64, N_NODES / 64), dim3(16, 16), 0, stream>>>(
        x, W1, hlin1, F_IN, HD);

    // hlin2 = relu(gather(hlin1)+b1) @ W2   (one block per node)
    gather_gemm2_kernel<<<N_NODES, 256, 0, stream>>>(
        start, srcrow, enorm, deg, hlin1, b1, W2, hlin2);

    // z = gather(hlin2)+b2 ; Adec = z@dW1[:64]+db1 ; Bdec = z@dW1[64:]
    gather_dec_kernel<<<N_NODES / 4, 256, 0, stream>>>(
        start, srcrow, enorm, deg, hlin2, b2, dW1, db1, z, Adec, Bdec);

    decoder_kernel<<<dim3(N_NODES / 32, N_NODES / 32), dim3(16, 16), 0, stream>>>(
        Adec, Bdec, dW2, db2, adj);
}